// Round 7
// baseline (878.034 us; speedup 1.0000x reference)
//
#include <hip/hip_runtime.h>
#include <hip/hip_bf16.h>
#include <math.h>

// ---------------- problem constants ----------------
#define B_SZ   2
#define L_SZ   2048
#define DM     1024          // d_model
#define DI     2048          // d_inner
#define DS     16            // d_state
#define M_SZ   (B_SZ * L_SZ) // 4096 rows
#define N_XZ   (2 * DI)      // 4096

typedef short bf16x8 __attribute__((ext_vector_type(8)));
typedef float f32x4  __attribute__((ext_vector_type(4)));

// pack two fp32 -> two bf16 (RNE) in one dword (a=lo, b=hi)
__device__ __forceinline__ unsigned int pk_bf16(float a, float b) {
  unsigned int ua = __builtin_bit_cast(unsigned int, a);
  unsigned int ub = __builtin_bit_cast(unsigned int, b);
  ua += 0x7FFFu + ((ua >> 16) & 1u);
  ub += 0x7FFFu + ((ub >> 16) & 1u);
  return (ua >> 16) | (ub & 0xFFFF0000u);
}

// ---------------- fp32 GEMM for xi half (feeds the scan -> MUST stay fp32) ----------------
// Round-5 lesson: bf16 xi -> absmax 16 (scan amplifies ~4000x). Do not re-try.
// 128x128 tile, BK=16, 8x8/thread split 4+4 at +64; register prefetch of tile
// k+1 issued after LDS commit -> global latency hides behind 16 kk of FMA.
__global__ __launch_bounds__(256, 2) void gemm_xi_f32(
    const float* __restrict__ A,    // x (M_SZ x DM)
    const float* __restrict__ B,    // W_in (DM x N_XZ), cols 0..2047
    const float* __restrict__ bias, float* __restrict__ C) {  // xz, stride N_XZ
  __shared__ float As[16][132];   // transposed A tile, +4 pad
  __shared__ float Bs[16][128];
  const int tid = threadIdx.x;
  const int tr = tid >> 4;        // 0..15
  const int tc = tid & 15;        // 0..15
  const int row0 = blockIdx.y * 128, col0 = blockIdx.x * 128;

  // per-thread staging coords
  const int ar = tid >> 2, aq = tid & 3;          // A: row, k-quad (+128 rows for i=1)
  const int bk = tid >> 5, bq = tid & 31;         // B: k-row, col-quad (+8 k for i=1)

  float acc[8][8] = {};
  float4 pa[2], pb[2];

  // ---- preload tile k0=0 ----
  pa[0] = *(const float4*)(A + (size_t)(row0 + ar) * DM + aq * 4);
  pa[1] = *(const float4*)(A + (size_t)(row0 + 64 + ar) * DM + aq * 4);
  pb[0] = *(const float4*)(B + (size_t)bk * N_XZ + col0 + bq * 4);
  pb[1] = *(const float4*)(B + (size_t)(bk + 8) * N_XZ + col0 + bq * 4);

  for (int k0 = 0; k0 < DM; k0 += 16) {
    __syncthreads();              // LDS readers of previous tile done
    // commit prefetched tile to LDS
    As[aq * 4 + 0][ar] = pa[0].x; As[aq * 4 + 1][ar] = pa[0].y;
    As[aq * 4 + 2][ar] = pa[0].z; As[aq * 4 + 3][ar] = pa[0].w;
    As[aq * 4 + 0][64 + ar] = pa[1].x; As[aq * 4 + 1][64 + ar] = pa[1].y;
    As[aq * 4 + 2][64 + ar] = pa[1].z; As[aq * 4 + 3][64 + ar] = pa[1].w;
    *(float4*)&Bs[bk][bq * 4]     = pb[0];
    *(float4*)&Bs[bk + 8][bq * 4] = pb[1];
    __syncthreads();
    // issue next tile's loads (in flight across the compute below)
    if (k0 + 16 < DM) {
      pa[0] = *(const float4*)(A + (size_t)(row0 + ar) * DM + k0 + 16 + aq * 4);
      pa[1] = *(const float4*)(A + (size_t)(row0 + 64 + ar) * DM + k0 + 16 + aq * 4);
      pb[0] = *(const float4*)(B + (size_t)(k0 + 16 + bk) * N_XZ + col0 + bq * 4);
      pb[1] = *(const float4*)(B + (size_t)(k0 + 24 + bk) * N_XZ + col0 + bq * 4);
    }
    #pragma unroll
    for (int kk = 0; kk < 16; ++kk) {
      float a[8], b[8];
      *(float4*)&a[0] = *(const float4*)&As[kk][tr * 4];
      *(float4*)&a[4] = *(const float4*)&As[kk][64 + tr * 4];
      *(float4*)&b[0] = *(const float4*)&Bs[kk][tc * 4];
      *(float4*)&b[4] = *(const float4*)&Bs[kk][64 + tc * 4];
      #pragma unroll
      for (int i2 = 0; i2 < 8; ++i2)
        #pragma unroll
        for (int j2 = 0; j2 < 8; ++j2)
          acc[i2][j2] = fmaf(a[i2], b[j2], acc[i2][j2]);
    }
  }
  #pragma unroll
  for (int ii = 0; ii < 2; ++ii)
    #pragma unroll
    for (int i = 0; i < 4; ++i) {
      int r = row0 + ii * 64 + tr * 4 + i;
      #pragma unroll
      for (int jj = 0; jj < 2; ++jj) {
        int c = col0 + jj * 64 + tc * 4;
        float4 o;
        o.x = acc[ii * 4 + i][jj * 4 + 0] + bias[c + 0];
        o.y = acc[ii * 4 + i][jj * 4 + 1] + bias[c + 1];
        o.z = acc[ii * 4 + i][jj * 4 + 2] + bias[c + 2];
        o.w = acc[ii * 4 + i][jj * 4 + 3] + bias[c + 3];
        *(float4*)(C + (size_t)r * N_XZ + c) = o;
      }
    }
}

// ---------------- bf16 MFMA GEMM, generalized strides + XCD-aware swizzle ----------------
// r6 lesson: sequential-block supertiles are a no-op (round-robin XCD dispatch
// undoes them). Instead: xcd = id&7 picks the column strip, so each XCD's 4 MB
// L2 holds its own B panel (~1 MB) for the whole kernel.
#define LDF 20   // uints per LDS row (32 bf16 data + 8 pad)
__global__ __launch_bounds__(256, 3) void gemm_mfma(
    const float* __restrict__ A, int lda,
    const float* __restrict__ B, int ldb,
    const float* __restrict__ bias, float* __restrict__ C, int ldc, int K,
    int col_blocks) {
  __shared__ unsigned int As[128 * LDF];  // [row][k] bf16 pairs
  __shared__ unsigned int Bs[128 * LDF];  // [col][k] bf16 pairs (transposed)
  const int tid  = threadIdx.x;
  const int lane = tid & 63, wave = tid >> 6;
  const int wr = wave >> 1, wc = wave & 1;
  const int lm = lane & 15, lq = lane >> 4;
  // XCD-aware mapping: assume block i -> XCD i%8 (perf heuristic only)
  const int rows = (int)(gridDim.x) / col_blocks;
  const int xcd  = blockIdx.x & 7;
  const int slot = blockIdx.x >> 3;
  const int cpx  = col_blocks >> 3;           // col-blocks per XCD (2 for z, 1 for out)
  const int colb = xcd * cpx + slot / rows;
  const int rowb = slot % rows;
  const int row0 = rowb * 128, col0 = colb * 128;

  f32x4 acc[4][4];
  #pragma unroll
  for (int i = 0; i < 4; ++i)
    #pragma unroll
    for (int j = 0; j < 4; ++j) acc[i][j] = (f32x4){0.f, 0.f, 0.f, 0.f};

  for (int k0 = 0; k0 < K; k0 += 32) {
    __syncthreads();
    // A: 128 rows x 32 k; float4 along k -> bf16x4 (8B) store
    #pragma unroll
    for (int i = 0; i < 4; ++i) {
      int idx = tid + i * 256, r = idx >> 3, q = idx & 7;
      float4 v = *(const float4*)(A + (size_t)(row0 + r) * lda + k0 + q * 4);
      *(uint2*)&As[r * LDF + q * 2] =
          make_uint2(pk_bf16(v.x, v.y), pk_bf16(v.z, v.w));
    }
    // B: 32 k x 128 n -> [n][k]; gather 4 k's per n (coalesced over n)
    #pragma unroll
    for (int i = 0; i < 4; ++i) {
      int idx = tid + i * 256, n = idx & 127, kq = idx >> 7;
      const float* bp = B + (size_t)(k0 + kq * 4) * ldb + col0 + n;
      float b0 = bp[0], b1 = bp[ldb], b2 = bp[2 * ldb], b3 = bp[3 * ldb];
      *(uint2*)&Bs[n * LDF + kq * 2] =
          make_uint2(pk_bf16(b0, b1), pk_bf16(b2, b3));
    }
    __syncthreads();
    bf16x8 af[4], bf[4];
    #pragma unroll
    for (int i = 0; i < 4; ++i)
      af[i] = *(const bf16x8*)&As[(wr * 64 + i * 16 + lm) * LDF + lq * 4];
    #pragma unroll
    for (int j = 0; j < 4; ++j)
      bf[j] = *(const bf16x8*)&Bs[(wc * 64 + j * 16 + lm) * LDF + lq * 4];
    #pragma unroll
    for (int i = 0; i < 4; ++i)
      #pragma unroll
      for (int j = 0; j < 4; ++j)
        acc[i][j] = __builtin_amdgcn_mfma_f32_16x16x32_bf16(af[i], bf[j], acc[i][j], 0, 0, 0);
  }
  // epilogue: C/D layout col=lane&15, row=(lane>>4)*4+reg
  #pragma unroll
  for (int i = 0; i < 4; ++i) {
    int r = row0 + wr * 64 + i * 16 + lq * 4;
    #pragma unroll
    for (int j = 0; j < 4; ++j) {
      int c = col0 + wc * 64 + j * 16 + lm;
      float bs = bias[c];
      #pragma unroll
      for (int k = 0; k < 4; ++k)
        C[(size_t)(r + k) * ldc + c] = acc[i][j][k] + bs;
    }
  }
}

// ---------------- depthwise causal conv (k=4, left pad 3) + SiLU ----------------
__global__ __launch_bounds__(256) void conv_silu_kernel(
    const float* __restrict__ xz, const float* __restrict__ Wc,
    const float* __restrict__ bc, float* __restrict__ xc) {
  int idx = blockIdx.x * blockDim.x + threadIdx.x;   // over M_SZ*DI
  if (idx >= M_SZ * DI) return;
  int d  = idx & (DI - 1);
  int bl = idx >> 11;            // row index (b*L + l), DI = 2^11
  int l  = bl & (L_SZ - 1);
  float4 w = ((const float4*)Wc)[d];  // W_conv[d][0][0..3]
  const float* base = xz + (size_t)bl * N_XZ + d;
  float s = bc[d] + base[0] * w.w;                     // k=3 tap -> current t
  if (l >= 1) s = fmaf(base[-N_XZ],     w.z, s);
  if (l >= 2) s = fmaf(base[-2 * N_XZ], w.y, s);
  if (l >= 3) s = fmaf(base[-3 * N_XZ], w.x, s);
  float sig = 1.f / (1.f + expf(-s));
  xc[idx] = s * sig;
}

// ---------------- skinny GEMM: Bm = xc @ W_B + b_B ; Cm = xc @ W_C + b_C ----------------
__global__ __launch_bounds__(256) void gemm_bc_kernel(
    const float* __restrict__ xc,
    const float* __restrict__ WB, const float* __restrict__ bB,
    const float* __restrict__ WC, const float* __restrict__ bC,
    float* __restrict__ Bm, float* __restrict__ Cm) {
  int t = blockIdx.x * blockDim.x + threadIdx.x;  // M_SZ*32
  int row = t >> 5;
  int cc  = t & 31;
  int s   = cc & 15;
  const float* W = (cc < 16) ? WB : WC;
  const float4* xr4 = (const float4*)(xc + (size_t)row * DI);
  float acc = 0.f;
  #pragma unroll 4
  for (int k4 = 0; k4 < DI / 4; ++k4) {
    float4 xv = xr4[k4];
    int k = k4 * 4;
    acc = fmaf(xv.x, W[(k    ) * DS + s], acc);
    acc = fmaf(xv.y, W[(k + 1) * DS + s], acc);
    acc = fmaf(xv.z, W[(k + 2) * DS + s], acc);
    acc = fmaf(xv.w, W[(k + 3) * DS + s], acc);
  }
  if (cc < 16) Bm[row * DS + s] = acc + bB[s];
  else         Cm[row * DS + s] = acc + bC[s];
}

// ---------------- selective scan: barrier-free single-wave blocks ----------------
// 1024 blocks x 64 thr; block = 4 channels x 16 states (one wave).
// No __syncthreads: all LDS producer/consumer pairs are same-wave (in-order
// LDS pipe). Register prefetch of next chunk overlaps global latency.
// Validated r6: absmax 0.5 with fp32 xi.
#define SCH   4     // channels per block
#define CHUNK 64
#define XSTR  66    // Xs2 [ch][l] padded stride
#define PSTR  68    // Ps  [l][tid] padded stride
__global__ __launch_bounds__(64) void scan_kernel(
    const float* xc, const float* __restrict__ xz,
    const float* __restrict__ Bm, const float* __restrict__ Cm,
    const float* __restrict__ A_log, const float* __restrict__ Dv,
    float* yg) {
  const int b   = blockIdx.y;
  const int d0  = blockIdx.x * SCH;
  const int tid = threadIdx.x;   // 0..63
  const int dd  = tid >> 4;      // 0..3  channel
  const int s   = tid & 15;      // state

  __shared__ float Xs2[SCH * XSTR];     // [ch][l]
  __shared__ float Zs[CHUNK * SCH];     // [l][ch]
  __shared__ float BCs[CHUNK * DS * 2]; // [l][s][{B,C}] interleaved
  __shared__ float Ps[CHUNK * PSTR];    // [l][tid] partial h*C

  float Alog = A_log[(d0 + dd) * DS + s];
  Alog = fminf(fmaxf(Alog, -10.f), 2.f);
  const float A  = -expf(Alog);
  const float Dr = Dv[d0 + (tid & 3)];
  float h = 0.f;

  const size_t rbase = (size_t)b * L_SZ;

  float4 pX, pZ, pB[4], pC[4];
  {
    size_t row = rbase + tid;
    pX = *(const float4*)(xc + row * DI + d0);
    pZ = *(const float4*)(xz + row * N_XZ + DI + d0);
    #pragma unroll
    for (int i = 0; i < 4; ++i) {
      int idx = tid + i * 64;
      size_t rr = rbase + (idx >> 2);
      pB[i] = *(const float4*)(Bm + rr * DS + (idx & 3) * 4);
      pC[i] = *(const float4*)(Cm + rr * DS + (idx & 3) * 4);
    }
  }

  for (int l0 = 0; l0 < L_SZ; l0 += CHUNK) {
    Xs2[0 * XSTR + tid] = pX.x;
    Xs2[1 * XSTR + tid] = pX.y;
    Xs2[2 * XSTR + tid] = pX.z;
    Xs2[3 * XSTR + tid] = pX.w;
    *(float4*)(Zs + tid * 4) = pZ;
    #pragma unroll
    for (int i = 0; i < 4; ++i) {
      int idx = tid + i * 64;
      float* bb = BCs + idx * 8;
      *(float2*)(bb + 0) = make_float2(pB[i].x, pC[i].x);
      *(float2*)(bb + 2) = make_float2(pB[i].y, pC[i].y);
      *(float2*)(bb + 4) = make_float2(pB[i].z, pC[i].z);
      *(float2*)(bb + 6) = make_float2(pB[i].w, pC[i].w);
    }
    if (l0 + CHUNK < L_SZ) {
      size_t row = rbase + l0 + CHUNK + tid;
      pX = *(const float4*)(xc + row * DI + d0);
      pZ = *(const float4*)(xz + row * N_XZ + DI + d0);
      #pragma unroll
      for (int i = 0; i < 4; ++i) {
        int idx = tid + i * 64;
        size_t rr = rbase + l0 + CHUNK + (idx >> 2);
        pB[i] = *(const float4*)(Bm + rr * DS + (idx & 3) * 4);
        pC[i] = *(const float4*)(Cm + rr * DS + (idx & 3) * 4);
      }
    }
    #pragma unroll 8
    for (int l = 0; l < CHUNK; l += 2) {
      float2 x2  = *(const float2*)&Xs2[dd * XSTR + l];
      float2 bc0 = *(const float2*)&BCs[l * 32 + s * 2];
      float2 bc1 = *(const float2*)&BCs[(l + 1) * 32 + s * 2];
      h = fmaf(h, A, x2.x * bc0.x);
      h = fminf(fmaxf(h, -100.f), 100.f);
      float p0 = h * bc0.y;
      h = fmaf(h, A, x2.y * bc1.x);
      h = fminf(fmaxf(h, -100.f), 100.f);
      float p1 = h * bc1.y;
      Ps[l * PSTR + tid]       = p0;
      Ps[(l + 1) * PSTR + tid] = p1;
    }
    #pragma unroll
    for (int i = 0; i < 4; ++i) {
      int idx = tid + i * 64;
      int l   = idx >> 2;
      int ddr = idx & 3;
      const float* pp = Ps + l * PSTR + ddr * 16;
      float4 a0 = *(const float4*)(pp + 0);
      float4 a1 = *(const float4*)(pp + 4);
      float4 a2 = *(const float4*)(pp + 8);
      float4 a3 = *(const float4*)(pp + 12);
      float t0 = (a0.x + a0.y) + (a0.z + a0.w);
      float t1 = (a1.x + a1.y) + (a1.z + a1.w);
      float t2 = (a2.x + a2.y) + (a2.z + a2.w);
      float t3 = (a3.x + a3.y) + (a3.z + a3.w);
      float sum = (t0 + t1) + (t2 + t3);
      float xv = Xs2[ddr * XSTR + l];
      float y  = fmaf(Dr, xv, sum);
      y = fminf(fmaxf(y, -100.f), 100.f);
      float g = 1.f / (1.f + expf(-Zs[l * 4 + ddr]));
      yg[(rbase + l0 + l) * DI + d0 + ddr] = y * g;
    }
  }
}

// ---------------- launch ----------------
extern "C" void kernel_launch(void* const* d_in, const int* in_sizes, int n_in,
                              void* d_out, int out_size, void* d_ws, size_t ws_size,
                              hipStream_t stream) {
  const float* x      = (const float*)d_in[0];
  const float* W_in   = (const float*)d_in[1];
  const float* b_in   = (const float*)d_in[2];
  const float* W_conv = (const float*)d_in[3];
  const float* b_conv = (const float*)d_in[4];
  const float* A_log  = (const float*)d_in[5];
  const float* Dv     = (const float*)d_in[6];
  const float* W_B    = (const float*)d_in[7];
  const float* b_B    = (const float*)d_in[8];
  const float* W_C    = (const float*)d_in[9];
  const float* b_C    = (const float*)d_in[10];
  const float* W_out  = (const float*)d_in[11];
  const float* b_out  = (const float*)d_in[12];
  float* out = (float*)d_out;

  float* ws = (float*)d_ws;
  float* xz = ws;                       // M_SZ*N_XZ
  float* xc = ws + (size_t)M_SZ * N_XZ; // M_SZ*DI
  float* Bm = xc + (size_t)M_SZ * DI;   // M_SZ*DS
  float* Cm = Bm + (size_t)M_SZ * DS;   // M_SZ*DS
  float* yg = xc;                       // alias: disjoint rows/cols per block

  // 1a) xi half: fp32 + register prefetch (scan-sensitive — bf16 fails, r5)
  {
    dim3 grid(DI / 128, M_SZ / 128);   // (16, 32)
    gemm_xi_f32<<<grid, 256, 0, stream>>>(x, W_in, b_in, xz);
  }
  // 1b) z half: bf16 MFMA with XCD-aware swizzle (gate path)
  {
    int col_blocks = DI / 128;          // 16
    int nblk = (M_SZ / 128) * col_blocks;
    gemm_mfma<<<nblk, 256, 0, stream>>>(x, DM, W_in + DI, N_XZ,
                                        b_in + DI, xz + DI, N_XZ, DM, col_blocks);
  }
  // 2) xc = silu(causal_dwconv(xi) + b_conv)
  {
    int n = M_SZ * DI;
    conv_silu_kernel<<<n / 256, 256, 0, stream>>>(xz, W_conv, b_conv, xc);
  }
  // 3) Bm, Cm projections (fp32 on conv output)
  {
    int n = M_SZ * 32;
    gemm_bc_kernel<<<n / 256, 256, 0, stream>>>(xc, W_B, b_B, W_C, b_C, Bm, Cm);
  }
  // 4) selective scan + gating (barrier-free, 1024 single-wave blocks)
  {
    dim3 grid(DI / SCH, B_SZ);           // (512, 2)
    scan_kernel<<<grid, 64, 0, stream>>>(xc, xz, Bm, Cm, A_log, Dv, yg);
  }
  // 5) out = yg @ W_out + b_out   (4096 x 1024 x 2048), bf16 MFMA + XCD swizzle
  {
    int col_blocks = DM / 128;          // 8
    int nblk = (M_SZ / 128) * col_blocks;
    gemm_mfma<<<nblk, 256, 0, stream>>>(yg, DI, W_out, DM, b_out, out, DM, DI, col_blocks);
  }
}

// Round 8
// 451.477 us; speedup vs baseline: 1.9448x; 1.9448x over previous
//
#include <hip/hip_runtime.h>
#include <hip/hip_bf16.h>
#include <math.h>

// ---------------- problem constants ----------------
#define B_SZ   2
#define L_SZ   2048
#define DM     1024          // d_model
#define DI     2048          // d_inner
#define DS     16            // d_state
#define M_SZ   (B_SZ * L_SZ) // 4096 rows
#define N_XZ   (2 * DI)      // 4096
#define LDF    20            // uints per LDS row (32 bf16 + 8 pad)

typedef short bf16x8 __attribute__((ext_vector_type(8)));
typedef float f32x4  __attribute__((ext_vector_type(4)));

__device__ __forceinline__ unsigned short rne16(float f) {
  unsigned int u = __builtin_bit_cast(unsigned int, f);
  u += 0x7FFFu + ((u >> 16) & 1u);
  return (unsigned short)(u >> 16);
}
__device__ __forceinline__ float frombf(unsigned short h) {
  unsigned int u = ((unsigned int)h) << 16;
  return __builtin_bit_cast(float, u);
}

// ---------------- x -> (x_hi, x_lo) bf16 split ----------------
__global__ __launch_bounds__(256) void convert_x(
    const float* __restrict__ x, unsigned short* __restrict__ xh,
    unsigned short* __restrict__ xl) {
  int i = (blockIdx.x * 256 + threadIdx.x) * 4;
  float4 v = *(const float4*)(x + i);
  unsigned short h0 = rne16(v.x), h1 = rne16(v.y), h2 = rne16(v.z), h3 = rne16(v.w);
  *(ushort4*)(xh + i) = make_ushort4(h0, h1, h2, h3);
  *(ushort4*)(xl + i) = make_ushort4(rne16(v.x - frombf(h0)), rne16(v.y - frombf(h1)),
                                     rne16(v.z - frombf(h2)), rne16(v.w - frombf(h3)));
}

// ---------------- W (RxC fp32) -> W^T (CxR) bf16 hi (+lo) ----------------
__global__ __launch_bounds__(256) void transpose_w(
    const float* __restrict__ in, int R, int C,
    unsigned short* __restrict__ oh, unsigned short* __restrict__ ol) {
  __shared__ float T[64][65];
  const int tid = threadIdx.x;
  const int c0 = blockIdx.x * 64, r0 = blockIdx.y * 64;
  const int cc = tid & 63, rq = tid >> 6;
  #pragma unroll
  for (int i = 0; i < 16; ++i) {
    int r = rq * 16 + i;
    T[r][cc] = in[(size_t)(r0 + r) * C + c0 + cc];
  }
  __syncthreads();
  #pragma unroll
  for (int i = 0; i < 16; ++i) {
    int c = rq * 16 + i;
    float v = T[cc][c];
    size_t o = (size_t)(c0 + c) * R + r0 + cc;
    unsigned short h = rne16(v);
    oh[o] = h;
    if (ol) ol[o] = rne16(v - frombf(h));
  }
}

// ---------------- bf16 MFMA GEMM (optionally bf16x3), pre-converted inputs ----------------
// A: M x K bf16 row-major (hi[, lo]); B: N x K bf16 row-major (pre-transposed, hi[, lo]).
// X3: D = Ah*Bh + Ah*Bl + Al*Bh  (~2^-17 relative error vs fp32).
// SPLITZ (GEMM1): cols < DI -> fp32 xi buffer; cols >= DI -> bf16 z buffer.
template<int BN, bool X3, bool SPLITZ>
__global__ __launch_bounds__(256, X3 ? 3 : 4) void gemm_t(
    const unsigned short* __restrict__ Ah, const unsigned short* __restrict__ Al, int lda,
    const unsigned short* __restrict__ Bh, const unsigned short* __restrict__ Bl, int ldb,
    const float* __restrict__ bias, float* __restrict__ Cf,
    unsigned short* __restrict__ Cz, int ldc, int K) {
  constexpr int WN  = BN / 2;      // wave col extent
  constexpr int FJ  = BN / 32;     // col frags per wave
  constexpr int BCH = BN / 64;     // B staging chunks per thread
  __shared__ unsigned int AhS[128 * LDF];
  __shared__ unsigned int BhS[BN * LDF];
  __shared__ unsigned int AlS[X3 ? 128 * LDF : 4];
  __shared__ unsigned int BlS[X3 ? BN * LDF : 4];
  const int tid  = threadIdx.x;
  const int lane = tid & 63, wave = tid >> 6;
  const int wr = wave >> 1, wc = wave & 1;
  const int lm = lane & 15, lq = lane >> 4;
  const int row0 = blockIdx.y * 128, col0 = blockIdx.x * BN;

  f32x4 acc[4][FJ];
  #pragma unroll
  for (int i = 0; i < 4; ++i)
    #pragma unroll
    for (int j = 0; j < FJ; ++j) acc[i][j] = (f32x4){0.f, 0.f, 0.f, 0.f};

  for (int k0 = 0; k0 < K; k0 += 32) {
    __syncthreads();
    // A tiles: 128 rows x 32 k, uint4 (8 bf16) per chunk
    #pragma unroll
    for (int i = 0; i < 2; ++i) {
      int idx = tid + i * 256, r = idx >> 2, q = idx & 3;
      size_t go = (size_t)(row0 + r) * lda + k0 + q * 8;
      *(uint4*)&AhS[r * LDF + q * 4] = *(const uint4*)(Ah + go);
      if constexpr (X3)
        *(uint4*)&AlS[r * LDF + q * 4] = *(const uint4*)(Al + go);
    }
    // B tiles: BN rows (n) x 32 k
    #pragma unroll
    for (int i = 0; i < BCH; ++i) {
      int idx = tid + i * 256, r = idx >> 2, q = idx & 3;
      size_t go = (size_t)(col0 + r) * ldb + k0 + q * 8;
      *(uint4*)&BhS[r * LDF + q * 4] = *(const uint4*)(Bh + go);
      if constexpr (X3)
        *(uint4*)&BlS[r * LDF + q * 4] = *(const uint4*)(Bl + go);
    }
    __syncthreads();
    bf16x8 bh[FJ], bl[FJ];
    #pragma unroll
    for (int j = 0; j < FJ; ++j) {
      bh[j] = *(const bf16x8*)&BhS[(wc * WN + j * 16 + lm) * LDF + lq * 4];
      if constexpr (X3)
        bl[j] = *(const bf16x8*)&BlS[(wc * WN + j * 16 + lm) * LDF + lq * 4];
    }
    #pragma unroll
    for (int i = 0; i < 4; ++i) {
      bf16x8 ah = *(const bf16x8*)&AhS[(wr * 64 + i * 16 + lm) * LDF + lq * 4];
      bf16x8 al;
      if constexpr (X3)
        al = *(const bf16x8*)&AlS[(wr * 64 + i * 16 + lm) * LDF + lq * 4];
      #pragma unroll
      for (int j = 0; j < FJ; ++j) {
        acc[i][j] = __builtin_amdgcn_mfma_f32_16x16x32_bf16(ah, bh[j], acc[i][j], 0, 0, 0);
        if constexpr (X3) {
          acc[i][j] = __builtin_amdgcn_mfma_f32_16x16x32_bf16(ah, bl[j], acc[i][j], 0, 0, 0);
          acc[i][j] = __builtin_amdgcn_mfma_f32_16x16x32_bf16(al, bh[j], acc[i][j], 0, 0, 0);
        }
      }
    }
  }
  // epilogue: C/D layout col=lane&15, row=(lane>>4)*4+reg
  #pragma unroll
  for (int i = 0; i < 4; ++i) {
    #pragma unroll
    for (int j = 0; j < FJ; ++j) {
      int c = col0 + wc * WN + j * 16 + lm;
      float bs = bias[c];
      #pragma unroll
      for (int k = 0; k < 4; ++k) {
        int r = row0 + wr * 64 + i * 16 + lq * 4 + k;
        float v = acc[i][j][k] + bs;
        if constexpr (SPLITZ) {
          if (c >= DI) Cz[(size_t)r * DI + (c - DI)] = rne16(v);
          else         Cf[(size_t)r * DI + c] = v;
        } else {
          Cf[(size_t)r * ldc + c] = v;
        }
      }
    }
  }
}

// ---------------- depthwise causal conv (k=4, left pad 3) + SiLU ----------------
// reads xi (M x DI fp32), writes xc (M x DI fp32)
__global__ __launch_bounds__(256) void conv_silu_kernel(
    const float* __restrict__ xi, const float* __restrict__ Wc,
    const float* __restrict__ bc, float* __restrict__ xc) {
  int idx = blockIdx.x * blockDim.x + threadIdx.x;   // over M_SZ*DI
  if (idx >= M_SZ * DI) return;
  int d  = idx & (DI - 1);
  int bl = idx >> 11;            // row (b*L + l)
  int l  = bl & (L_SZ - 1);
  float4 w = ((const float4*)Wc)[d];
  const float* base = xi + (size_t)bl * DI + d;
  float s = bc[d] + base[0] * w.w;
  if (l >= 1) s = fmaf(base[-DI],     w.z, s);
  if (l >= 2) s = fmaf(base[-2 * DI], w.y, s);
  if (l >= 3) s = fmaf(base[-3 * DI], w.x, s);
  float sig = 1.f / (1.f + expf(-s));
  xc[idx] = s * sig;
}

// ---------------- skinny GEMM: Bm = xc @ W_B + b_B ; Cm = xc @ W_C + b_C ----------------
__global__ __launch_bounds__(256) void gemm_bc_kernel(
    const float* __restrict__ xc,
    const float* __restrict__ WB, const float* __restrict__ bB,
    const float* __restrict__ WC, const float* __restrict__ bC,
    float* __restrict__ Bm, float* __restrict__ Cm) {
  int t = blockIdx.x * blockDim.x + threadIdx.x;  // M_SZ*32
  int row = t >> 5;
  int cc  = t & 31;
  int s   = cc & 15;
  const float* W = (cc < 16) ? WB : WC;
  const float4* xr4 = (const float4*)(xc + (size_t)row * DI);
  float acc = 0.f;
  #pragma unroll 4
  for (int k4 = 0; k4 < DI / 4; ++k4) {
    float4 xv = xr4[k4];
    int k = k4 * 4;
    acc = fmaf(xv.x, W[(k    ) * DS + s], acc);
    acc = fmaf(xv.y, W[(k + 1) * DS + s], acc);
    acc = fmaf(xv.z, W[(k + 2) * DS + s], acc);
    acc = fmaf(xv.w, W[(k + 3) * DS + s], acc);
  }
  if (cc < 16) Bm[row * DS + s] = acc + bB[s];
  else         Cm[row * DS + s] = acc + bC[s];
}

// ---------------- selective scan: barrier-free single-wave blocks ----------------
// Validated r6 (absmax 0.5 with fp32 xi). Changes: z input is bf16, yg output bf16.
#define SCH   4     // channels per block
#define CHUNK 64
#define XSTR  66    // Xs2 [ch][l] padded stride
#define PSTR  68    // Ps  [l][tid] padded stride
__global__ __launch_bounds__(64) void scan_kernel(
    const float* xc, const unsigned short* __restrict__ zb,
    const float* __restrict__ Bm, const float* __restrict__ Cm,
    const float* __restrict__ A_log, const float* __restrict__ Dv,
    unsigned short* yg) {
  const int b   = blockIdx.y;
  const int d0  = blockIdx.x * SCH;
  const int tid = threadIdx.x;   // 0..63
  const int dd  = tid >> 4;      // 0..3  channel
  const int s   = tid & 15;      // state

  __shared__ float Xs2[SCH * XSTR];     // [ch][l]
  __shared__ float Zs[CHUNK * SCH];     // [l][ch]
  __shared__ float BCs[CHUNK * DS * 2]; // [l][s][{B,C}] interleaved
  __shared__ float Ps[CHUNK * PSTR];    // [l][tid] partial h*C

  float Alog = A_log[(d0 + dd) * DS + s];
  Alog = fminf(fmaxf(Alog, -10.f), 2.f);
  const float A  = -expf(Alog);
  const float Dr = Dv[d0 + (tid & 3)];
  float h = 0.f;

  const size_t rbase = (size_t)b * L_SZ;

  float4 pX, pB[4], pC[4];
  uint2 pZ;
  {
    size_t row = rbase + tid;
    pX = *(const float4*)(xc + row * DI + d0);
    pZ = *(const uint2*)(zb + row * DI + d0);
    #pragma unroll
    for (int i = 0; i < 4; ++i) {
      int idx = tid + i * 64;
      size_t rr = rbase + (idx >> 2);
      pB[i] = *(const float4*)(Bm + rr * DS + (idx & 3) * 4);
      pC[i] = *(const float4*)(Cm + rr * DS + (idx & 3) * 4);
    }
  }

  for (int l0 = 0; l0 < L_SZ; l0 += CHUNK) {
    Xs2[0 * XSTR + tid] = pX.x;
    Xs2[1 * XSTR + tid] = pX.y;
    Xs2[2 * XSTR + tid] = pX.z;
    Xs2[3 * XSTR + tid] = pX.w;
    *(float4*)(Zs + tid * 4) = make_float4(
        frombf((unsigned short)(pZ.x & 0xFFFF)), frombf((unsigned short)(pZ.x >> 16)),
        frombf((unsigned short)(pZ.y & 0xFFFF)), frombf((unsigned short)(pZ.y >> 16)));
    #pragma unroll
    for (int i = 0; i < 4; ++i) {
      int idx = tid + i * 64;
      float* bb = BCs + idx * 8;
      *(float2*)(bb + 0) = make_float2(pB[i].x, pC[i].x);
      *(float2*)(bb + 2) = make_float2(pB[i].y, pC[i].y);
      *(float2*)(bb + 4) = make_float2(pB[i].z, pC[i].z);
      *(float2*)(bb + 6) = make_float2(pB[i].w, pC[i].w);
    }
    if (l0 + CHUNK < L_SZ) {
      size_t row = rbase + l0 + CHUNK + tid;
      pX = *(const float4*)(xc + row * DI + d0);
      pZ = *(const uint2*)(zb + row * DI + d0);
      #pragma unroll
      for (int i = 0; i < 4; ++i) {
        int idx = tid + i * 64;
        size_t rr = rbase + l0 + CHUNK + (idx >> 2);
        pB[i] = *(const float4*)(Bm + rr * DS + (idx & 3) * 4);
        pC[i] = *(const float4*)(Cm + rr * DS + (idx & 3) * 4);
      }
    }
    #pragma unroll 8
    for (int l = 0; l < CHUNK; l += 2) {
      float2 x2  = *(const float2*)&Xs2[dd * XSTR + l];
      float2 bc0 = *(const float2*)&BCs[l * 32 + s * 2];
      float2 bc1 = *(const float2*)&BCs[(l + 1) * 32 + s * 2];
      h = fmaf(h, A, x2.x * bc0.x);
      h = fminf(fmaxf(h, -100.f), 100.f);
      float p0 = h * bc0.y;
      h = fmaf(h, A, x2.y * bc1.x);
      h = fminf(fmaxf(h, -100.f), 100.f);
      float p1 = h * bc1.y;
      Ps[l * PSTR + tid]       = p0;
      Ps[(l + 1) * PSTR + tid] = p1;
    }
    #pragma unroll
    for (int i = 0; i < 4; ++i) {
      int idx = tid + i * 64;
      int l   = idx >> 2;
      int ddr = idx & 3;
      const float* pp = Ps + l * PSTR + ddr * 16;
      float4 a0 = *(const float4*)(pp + 0);
      float4 a1 = *(const float4*)(pp + 4);
      float4 a2 = *(const float4*)(pp + 8);
      float4 a3 = *(const float4*)(pp + 12);
      float t0 = (a0.x + a0.y) + (a0.z + a0.w);
      float t1 = (a1.x + a1.y) + (a1.z + a1.w);
      float t2 = (a2.x + a2.y) + (a2.z + a2.w);
      float t3 = (a3.x + a3.y) + (a3.z + a3.w);
      float sum = (t0 + t1) + (t2 + t3);
      float xv = Xs2[ddr * XSTR + l];
      float y  = fmaf(Dr, xv, sum);
      y = fminf(fmaxf(y, -100.f), 100.f);
      float g = 1.f / (1.f + expf(-Zs[l * 4 + ddr]));
      yg[(rbase + l0 + l) * DI + d0 + ddr] = rne16(y * g);
    }
  }
}

// ---------------- launch ----------------
// ws layout (bytes), peak 88.6 MB:
//   [0,        33554432)  xi fp32 (GEMM1 out, conv in); first 16 MB reused as yg bf16 after conv
//   [33554432, 50331648)  z bf16
//   [50331648, 83886080)  xc fp32 (conv out); BEFORE conv hosts xh/xl/WhT/WlT (8 MB each)
//   [83886080, 84148224)  Bm
//   [84148224, 84410368)  Cm
//   [84410368, 88604672)  WoutT bf16
extern "C" void kernel_launch(void* const* d_in, const int* in_sizes, int n_in,
                              void* d_out, int out_size, void* d_ws, size_t ws_size,
                              hipStream_t stream) {
  const float* x      = (const float*)d_in[0];
  const float* W_in   = (const float*)d_in[1];
  const float* b_in   = (const float*)d_in[2];
  const float* W_conv = (const float*)d_in[3];
  const float* b_conv = (const float*)d_in[4];
  const float* A_log  = (const float*)d_in[5];
  const float* Dv     = (const float*)d_in[6];
  const float* W_B    = (const float*)d_in[7];
  const float* b_B    = (const float*)d_in[8];
  const float* W_C    = (const float*)d_in[9];
  const float* b_C    = (const float*)d_in[10];
  const float* W_out  = (const float*)d_in[11];
  const float* b_out  = (const float*)d_in[12];
  float* out = (float*)d_out;

  char* w = (char*)d_ws;
  float*          xi   = (float*)(w + 0);
  unsigned short* yg   = (unsigned short*)(w + 0);          // reuse after conv
  unsigned short* zb   = (unsigned short*)(w + 33554432);
  float*          xc   = (float*)(w + 50331648);
  unsigned short* xh   = (unsigned short*)(w + 50331648);   // pre-conv phase
  unsigned short* xl   = (unsigned short*)(w + 58720256);
  unsigned short* WhT  = (unsigned short*)(w + 67108864);
  unsigned short* WlT  = (unsigned short*)(w + 75497472);
  float*          Bm   = (float*)(w + 83886080);
  float*          Cm   = (float*)(w + 84148224);
  unsigned short* WoT  = (unsigned short*)(w + 84410368);

  // 0a) x -> xh/xl
  convert_x<<<M_SZ * DM / 1024, 256, 0, stream>>>(x, xh, xl);
  // 0b) W_in (DM x N_XZ) -> WhT/WlT (N_XZ x DM)
  transpose_w<<<dim3(N_XZ / 64, DM / 64), 256, 0, stream>>>(W_in, DM, N_XZ, WhT, WlT);
  // 0c) W_out (DI x DM) -> WoT (DM x DI), hi only (post-scan path)
  transpose_w<<<dim3(DM / 64, DI / 64), 256, 0, stream>>>(W_out, DI, DM, WoT, nullptr);

  // 1) xz = x @ W_in + b_in via bf16x3 MFMA; xi half -> fp32, z half -> bf16
  gemm_t<128, true, true><<<dim3(N_XZ / 128, M_SZ / 128), 256, 0, stream>>>(
      xh, xl, DM, WhT, WlT, DM, b_in, xi, zb, DI, DM);

  // 2) xc = silu(causal_dwconv(xi) + b_conv)
  conv_silu_kernel<<<M_SZ * DI / 256, 256, 0, stream>>>(xi, W_conv, b_conv, xc);

  // 3) Bm, Cm projections (fp32)
  gemm_bc_kernel<<<M_SZ * 32 / 256, 256, 0, stream>>>(xc, W_B, b_B, W_C, b_C, Bm, Cm);

  // 4) selective scan + gating -> yg bf16 (overwrites dead xi region)
  scan_kernel<<<dim3(DI / SCH, B_SZ), 64, 0, stream>>>(xc, zb, Bm, Cm, A_log, Dv, yg);

  // 5) out = yg @ W_out + b_out, pure bf16 MFMA (BN=64 -> 512 blocks)
  gemm_t<64, false, false><<<dim3(DM / 64, M_SZ / 128), 256, 0, stream>>>(
      yg, nullptr, DI, WoT, nullptr, DI, b_out, out, nullptr, DM, DI);
}

// Round 10
// 431.997 us; speedup vs baseline: 2.0325x; 1.0451x over previous
//
#include <hip/hip_runtime.h>
#include <hip/hip_bf16.h>
#include <math.h>

// ---------------- problem constants ----------------
#define B_SZ   2
#define L_SZ   2048
#define DM     1024          // d_model
#define DI     2048          // d_inner
#define DS     16            // d_state
#define M_SZ   (B_SZ * L_SZ) // 4096 rows
#define N_XZ   (2 * DI)      // 4096
#define LDF    20            // uints per LDS row (32 bf16 + 8 pad) -- r8-proven

typedef short bf16x8 __attribute__((ext_vector_type(8)));
typedef float f32x4  __attribute__((ext_vector_type(4)));

__device__ __forceinline__ unsigned short rne16(float f) {
  unsigned int u = __builtin_bit_cast(unsigned int, f);
  u += 0x7FFFu + ((u >> 16) & 1u);
  return (unsigned short)(u >> 16);
}
__device__ __forceinline__ float frombf(unsigned short h) {
  unsigned int u = ((unsigned int)h) << 16;
  return __builtin_bit_cast(float, u);
}

// ---------------- x -> (x_hi, x_lo) bf16 split ----------------
__global__ __launch_bounds__(256) void convert_x(
    const float* __restrict__ x, unsigned short* __restrict__ xh,
    unsigned short* __restrict__ xl) {
  int i = (blockIdx.x * 256 + threadIdx.x) * 4;
  float4 v = *(const float4*)(x + i);
  unsigned short h0 = rne16(v.x), h1 = rne16(v.y), h2 = rne16(v.z), h3 = rne16(v.w);
  *(ushort4*)(xh + i) = make_ushort4(h0, h1, h2, h3);
  *(ushort4*)(xl + i) = make_ushort4(rne16(v.x - frombf(h0)), rne16(v.y - frombf(h1)),
                                     rne16(v.z - frombf(h2)), rne16(v.w - frombf(h3)));
}

// ---------------- W (RxC fp32) -> W^T (CxR) bf16 hi (+lo) ----------------
__global__ __launch_bounds__(256) void transpose_w(
    const float* __restrict__ in, int R, int C,
    unsigned short* __restrict__ oh, unsigned short* __restrict__ ol) {
  __shared__ float T[64][65];
  const int tid = threadIdx.x;
  const int c0 = blockIdx.x * 64, r0 = blockIdx.y * 64;
  const int cc = tid & 63, rq = tid >> 6;
  #pragma unroll
  for (int i = 0; i < 16; ++i) {
    int r = rq * 16 + i;
    T[r][cc] = in[(size_t)(r0 + r) * C + c0 + cc];
  }
  __syncthreads();
  #pragma unroll
  for (int i = 0; i < 16; ++i) {
    int c = rq * 16 + i;
    float v = T[cc][c];
    size_t o = (size_t)(c0 + c) * R + r0 + cc;
    unsigned short h = rne16(v);
    oh[o] = h;
    if (ol) ol[o] = rne16(v - frombf(h));
  }
}

// ---------------- bf16 MFMA GEMM (optionally bf16x3), pre-converted inputs ----------------
// EXACT r8-proven body (LDF=20, launch_bounds (256, X3?3:4)); only the epilogue
// output path is parameterized (OUTBF16). r9's XOR-swizzle/lambda/bounds-4 caused
// unexplained cross-launch divergence -> withdrawn.
// A: M x K bf16 row-major (hi[, lo]); B: N x K bf16 row-major (pre-transposed).
// X3: D = Ah*Bh + Ah*Bl + Al*Bh (~2^-17 rel err vs fp32).
template<int BN, bool X3, bool OUTBF16>
__global__ __launch_bounds__(256, X3 ? 3 : 4) void gemm_t(
    const unsigned short* __restrict__ Ah, const unsigned short* __restrict__ Al, int lda,
    const unsigned short* __restrict__ Bh, const unsigned short* __restrict__ Bl, int ldb,
    const float* __restrict__ bias, float* __restrict__ Cf,
    unsigned short* __restrict__ Cz, int ldc, int K) {
  constexpr int WN  = BN / 2;      // wave col extent
  constexpr int FJ  = BN / 32;     // col frags per wave
  constexpr int BCH = BN / 64;     // B staging chunks per thread
  __shared__ unsigned int AhS[128 * LDF];
  __shared__ unsigned int BhS[BN * LDF];
  __shared__ unsigned int AlS[X3 ? 128 * LDF : 4];
  __shared__ unsigned int BlS[X3 ? BN * LDF : 4];
  const int tid  = threadIdx.x;
  const int lane = tid & 63, wave = tid >> 6;
  const int wr = wave >> 1, wc = wave & 1;
  const int lm = lane & 15, lq = lane >> 4;
  const int row0 = blockIdx.y * 128, col0 = blockIdx.x * BN;

  f32x4 acc[4][FJ];
  #pragma unroll
  for (int i = 0; i < 4; ++i)
    #pragma unroll
    for (int j = 0; j < FJ; ++j) acc[i][j] = (f32x4){0.f, 0.f, 0.f, 0.f};

  for (int k0 = 0; k0 < K; k0 += 32) {
    __syncthreads();
    // A tiles: 128 rows x 32 k, uint4 (8 bf16) per chunk
    #pragma unroll
    for (int i = 0; i < 2; ++i) {
      int idx = tid + i * 256, r = idx >> 2, q = idx & 3;
      size_t go = (size_t)(row0 + r) * lda + k0 + q * 8;
      *(uint4*)&AhS[r * LDF + q * 4] = *(const uint4*)(Ah + go);
      if constexpr (X3)
        *(uint4*)&AlS[r * LDF + q * 4] = *(const uint4*)(Al + go);
    }
    // B tiles: BN rows (n) x 32 k
    #pragma unroll
    for (int i = 0; i < BCH; ++i) {
      int idx = tid + i * 256, r = idx >> 2, q = idx & 3;
      size_t go = (size_t)(col0 + r) * ldb + k0 + q * 8;
      *(uint4*)&BhS[r * LDF + q * 4] = *(const uint4*)(Bh + go);
      if constexpr (X3)
        *(uint4*)&BlS[r * LDF + q * 4] = *(const uint4*)(Bl + go);
    }
    __syncthreads();
    bf16x8 bh[FJ], bl[FJ];
    #pragma unroll
    for (int j = 0; j < FJ; ++j) {
      bh[j] = *(const bf16x8*)&BhS[(wc * WN + j * 16 + lm) * LDF + lq * 4];
      if constexpr (X3)
        bl[j] = *(const bf16x8*)&BlS[(wc * WN + j * 16 + lm) * LDF + lq * 4];
    }
    #pragma unroll
    for (int i = 0; i < 4; ++i) {
      bf16x8 ah = *(const bf16x8*)&AhS[(wr * 64 + i * 16 + lm) * LDF + lq * 4];
      bf16x8 al;
      if constexpr (X3)
        al = *(const bf16x8*)&AlS[(wr * 64 + i * 16 + lm) * LDF + lq * 4];
      #pragma unroll
      for (int j = 0; j < FJ; ++j) {
        acc[i][j] = __builtin_amdgcn_mfma_f32_16x16x32_bf16(ah, bh[j], acc[i][j], 0, 0, 0);
        if constexpr (X3) {
          acc[i][j] = __builtin_amdgcn_mfma_f32_16x16x32_bf16(ah, bl[j], acc[i][j], 0, 0, 0);
          acc[i][j] = __builtin_amdgcn_mfma_f32_16x16x32_bf16(al, bh[j], acc[i][j], 0, 0, 0);
        }
      }
    }
  }
  // epilogue: C/D layout col=lane&15, row=(lane>>4)*4+reg
  #pragma unroll
  for (int i = 0; i < 4; ++i) {
    #pragma unroll
    for (int j = 0; j < FJ; ++j) {
      int c = col0 + wc * WN + j * 16 + lm;
      float bs = bias[c];
      #pragma unroll
      for (int k = 0; k < 4; ++k) {
        int r = row0 + wr * 64 + i * 16 + lq * 4 + k;
        float v = acc[i][j][k] + bs;
        if constexpr (OUTBF16) Cz[(size_t)r * ldc + c] = rne16(v);
        else                   Cf[(size_t)r * ldc + c] = v;
      }
    }
  }
}

// ---------------- depthwise causal conv (k=4, left pad 3) + SiLU ----------------
__global__ __launch_bounds__(256) void conv_silu_kernel(
    const float* __restrict__ xi, const float* __restrict__ Wc,
    const float* __restrict__ bc, float* __restrict__ xc) {
  int idx = blockIdx.x * blockDim.x + threadIdx.x;   // over M_SZ*DI
  if (idx >= M_SZ * DI) return;
  int d  = idx & (DI - 1);
  int bl = idx >> 11;            // row (b*L + l)
  int l  = bl & (L_SZ - 1);
  float4 w = ((const float4*)Wc)[d];
  const float* base = xi + (size_t)bl * DI + d;
  float s = bc[d] + base[0] * w.w;
  if (l >= 1) s = fmaf(base[-DI],     w.z, s);
  if (l >= 2) s = fmaf(base[-2 * DI], w.y, s);
  if (l >= 3) s = fmaf(base[-3 * DI], w.x, s);
  float sig = 1.f / (1.f + expf(-s));
  xc[idx] = s * sig;
}

// ---------------- skinny GEMM: Bm = xc @ W_B + b_B ; Cm = xc @ W_C + b_C ----------------
__global__ __launch_bounds__(256) void gemm_bc_kernel(
    const float* __restrict__ xc,
    const float* __restrict__ WB, const float* __restrict__ bB,
    const float* __restrict__ WC, const float* __restrict__ bC,
    float* __restrict__ Bm, float* __restrict__ Cm) {
  int t = blockIdx.x * blockDim.x + threadIdx.x;  // M_SZ*32
  int row = t >> 5;
  int cc  = t & 31;
  int s   = cc & 15;
  const float* W = (cc < 16) ? WB : WC;
  const float4* xr4 = (const float4*)(xc + (size_t)row * DI);
  float acc = 0.f;
  #pragma unroll 4
  for (int k4 = 0; k4 < DI / 4; ++k4) {
    float4 xv = xr4[k4];
    int k = k4 * 4;
    acc = fmaf(xv.x, W[(k    ) * DS + s], acc);
    acc = fmaf(xv.y, W[(k + 1) * DS + s], acc);
    acc = fmaf(xv.z, W[(k + 2) * DS + s], acc);
    acc = fmaf(xv.w, W[(k + 3) * DS + s], acc);
  }
  if (cc < 16) Bm[row * DS + s] = acc + bB[s];
  else         Cm[row * DS + s] = acc + bC[s];
}

// ---------------- selective scan: barrier-free single-wave blocks ----------------
// Validated r6/r8 (absmax 0.5, incl. post-timing). z input bf16, yg output bf16.
#define SCH   4     // channels per block
#define CHUNK 64
#define XSTR  66    // Xs2 [ch][l] padded stride
#define PSTR  68    // Ps  [l][tid] padded stride
__global__ __launch_bounds__(64) void scan_kernel(
    const float* xc, const unsigned short* __restrict__ zb,
    const float* __restrict__ Bm, const float* __restrict__ Cm,
    const float* __restrict__ A_log, const float* __restrict__ Dv,
    unsigned short* yg) {
  const int b   = blockIdx.y;
  const int d0  = blockIdx.x * SCH;
  const int tid = threadIdx.x;   // 0..63
  const int dd  = tid >> 4;      // 0..3  channel
  const int s   = tid & 15;      // state

  __shared__ float Xs2[SCH * XSTR];     // [ch][l]
  __shared__ float Zs[CHUNK * SCH];     // [l][ch]
  __shared__ float BCs[CHUNK * DS * 2]; // [l][s][{B,C}] interleaved
  __shared__ float Ps[CHUNK * PSTR];    // [l][tid] partial h*C

  float Alog = A_log[(d0 + dd) * DS + s];
  Alog = fminf(fmaxf(Alog, -10.f), 2.f);
  const float A  = -expf(Alog);
  const float Dr = Dv[d0 + (tid & 3)];
  float h = 0.f;

  const size_t rbase = (size_t)b * L_SZ;

  float4 pX, pB[4], pC[4];
  uint2 pZ;
  {
    size_t row = rbase + tid;
    pX = *(const float4*)(xc + row * DI + d0);
    pZ = *(const uint2*)(zb + row * DI + d0);
    #pragma unroll
    for (int i = 0; i < 4; ++i) {
      int idx = tid + i * 64;
      size_t rr = rbase + (idx >> 2);
      pB[i] = *(const float4*)(Bm + rr * DS + (idx & 3) * 4);
      pC[i] = *(const float4*)(Cm + rr * DS + (idx & 3) * 4);
    }
  }

  for (int l0 = 0; l0 < L_SZ; l0 += CHUNK) {
    Xs2[0 * XSTR + tid] = pX.x;
    Xs2[1 * XSTR + tid] = pX.y;
    Xs2[2 * XSTR + tid] = pX.z;
    Xs2[3 * XSTR + tid] = pX.w;
    *(float4*)(Zs + tid * 4) = make_float4(
        frombf((unsigned short)(pZ.x & 0xFFFF)), frombf((unsigned short)(pZ.x >> 16)),
        frombf((unsigned short)(pZ.y & 0xFFFF)), frombf((unsigned short)(pZ.y >> 16)));
    #pragma unroll
    for (int i = 0; i < 4; ++i) {
      int idx = tid + i * 64;
      float* bb = BCs + idx * 8;
      *(float2*)(bb + 0) = make_float2(pB[i].x, pC[i].x);
      *(float2*)(bb + 2) = make_float2(pB[i].y, pC[i].y);
      *(float2*)(bb + 4) = make_float2(pB[i].z, pC[i].z);
      *(float2*)(bb + 6) = make_float2(pB[i].w, pC[i].w);
    }
    if (l0 + CHUNK < L_SZ) {
      size_t row = rbase + l0 + CHUNK + tid;
      pX = *(const float4*)(xc + row * DI + d0);
      pZ = *(const uint2*)(zb + row * DI + d0);
      #pragma unroll
      for (int i = 0; i < 4; ++i) {
        int idx = tid + i * 64;
        size_t rr = rbase + l0 + CHUNK + (idx >> 2);
        pB[i] = *(const float4*)(Bm + rr * DS + (idx & 3) * 4);
        pC[i] = *(const float4*)(Cm + rr * DS + (idx & 3) * 4);
      }
    }
    #pragma unroll 8
    for (int l = 0; l < CHUNK; l += 2) {
      float2 x2  = *(const float2*)&Xs2[dd * XSTR + l];
      float2 bc0 = *(const float2*)&BCs[l * 32 + s * 2];
      float2 bc1 = *(const float2*)&BCs[(l + 1) * 32 + s * 2];
      h = fmaf(h, A, x2.x * bc0.x);
      h = fminf(fmaxf(h, -100.f), 100.f);
      float p0 = h * bc0.y;
      h = fmaf(h, A, x2.y * bc1.x);
      h = fminf(fmaxf(h, -100.f), 100.f);
      float p1 = h * bc1.y;
      Ps[l * PSTR + tid]       = p0;
      Ps[(l + 1) * PSTR + tid] = p1;
    }
    #pragma unroll
    for (int i = 0; i < 4; ++i) {
      int idx = tid + i * 64;
      int l   = idx >> 2;
      int ddr = idx & 3;
      const float* pp = Ps + l * PSTR + ddr * 16;
      float4 a0 = *(const float4*)(pp + 0);
      float4 a1 = *(const float4*)(pp + 4);
      float4 a2 = *(const float4*)(pp + 8);
      float4 a3 = *(const float4*)(pp + 12);
      float t0 = (a0.x + a0.y) + (a0.z + a0.w);
      float t1 = (a1.x + a1.y) + (a1.z + a1.w);
      float t2 = (a2.x + a2.y) + (a2.z + a2.w);
      float t3 = (a3.x + a3.y) + (a3.z + a3.w);
      float sum = (t0 + t1) + (t2 + t3);
      float xv = Xs2[ddr * XSTR + l];
      float y  = fmaf(Dr, xv, sum);
      y = fminf(fmaxf(y, -100.f), 100.f);
      float g = 1.f / (1.f + expf(-Zs[l * 4 + ddr]));
      yg[(rbase + l0 + l) * DI + d0 + ddr] = rne16(y * g);
    }
  }
}

// ---------------- launch ----------------
// ws layout (bytes), peak 88.6 MB:
//   [0,        33554432)  xi fp32 (GEMM1 out, conv in); first 16 MB reused as yg bf16 after conv
//   [33554432, 50331648)  z bf16
//   [50331648, 83886080)  xc fp32 (conv out); BEFORE conv hosts xh/xl/WhT/WlT (8 MB each)
//   [83886080, 84148224)  Bm
//   [84148224, 84410368)  Cm
//   [84410368, 88604672)  WoutT bf16
extern "C" void kernel_launch(void* const* d_in, const int* in_sizes, int n_in,
                              void* d_out, int out_size, void* d_ws, size_t ws_size,
                              hipStream_t stream) {
  const float* x      = (const float*)d_in[0];
  const float* W_in   = (const float*)d_in[1];
  const float* b_in   = (const float*)d_in[2];
  const float* W_conv = (const float*)d_in[3];
  const float* b_conv = (const float*)d_in[4];
  const float* A_log  = (const float*)d_in[5];
  const float* Dv     = (const float*)d_in[6];
  const float* W_B    = (const float*)d_in[7];
  const float* b_B    = (const float*)d_in[8];
  const float* W_C    = (const float*)d_in[9];
  const float* b_C    = (const float*)d_in[10];
  const float* W_out  = (const float*)d_in[11];
  const float* b_out  = (const float*)d_in[12];
  float* out = (float*)d_out;

  char* w = (char*)d_ws;
  float*          xi   = (float*)(w + 0);
  unsigned short* yg   = (unsigned short*)(w + 0);          // reuse after conv
  unsigned short* zb   = (unsigned short*)(w + 33554432);
  float*          xc   = (float*)(w + 50331648);
  unsigned short* xh   = (unsigned short*)(w + 50331648);   // pre-conv phase
  unsigned short* xl   = (unsigned short*)(w + 58720256);
  unsigned short* WhT  = (unsigned short*)(w + 67108864);
  unsigned short* WlT  = (unsigned short*)(w + 75497472);
  float*          Bm   = (float*)(w + 83886080);
  float*          Cm   = (float*)(w + 84148224);
  unsigned short* WoT  = (unsigned short*)(w + 84410368);

  // 0a) x -> xh/xl
  convert_x<<<M_SZ * DM / 1024, 256, 0, stream>>>(x, xh, xl);
  // 0b) W_in (DM x N_XZ) -> WhT/WlT (N_XZ x DM)
  transpose_w<<<dim3(N_XZ / 64, DM / 64), 256, 0, stream>>>(W_in, DM, N_XZ, WhT, WlT);
  // 0c) W_out (DI x DM) -> WoT (DM x DI), hi only (post-scan path)
  transpose_w<<<dim3(DM / 64, DI / 64), 256, 0, stream>>>(W_out, DI, DM, WoT, nullptr);

  // 1a) xi = x @ W_in[:, :DI] + b_in[:DI]  -- bf16x3 (scan-sensitive), fp32 out
  gemm_t<128, true, false><<<dim3(DI / 128, M_SZ / 128), 256, 0, stream>>>(
      xh, xl, DM, WhT, WlT, DM, b_in, xi, nullptr, DI, DM);

  // 1b) z = x @ W_in[:, DI:] + b_in[DI:]  -- plain bf16 (gate path), bf16 out
  gemm_t<128, false, true><<<dim3(DI / 128, M_SZ / 128), 256, 0, stream>>>(
      xh, nullptr, DM, WhT + (size_t)DI * DM, nullptr, DM,
      b_in + DI, nullptr, zb, DI, DM);

  // 2) xc = silu(causal_dwconv(xi) + b_conv)
  conv_silu_kernel<<<M_SZ * DI / 256, 256, 0, stream>>>(xi, W_conv, b_conv, xc);

  // 3) Bm, Cm projections (fp32)
  gemm_bc_kernel<<<M_SZ * 32 / 256, 256, 0, stream>>>(xc, W_B, b_B, W_C, b_C, Bm, Cm);

  // 4) selective scan + gating -> yg bf16 (overwrites dead xi region)
  scan_kernel<<<dim3(DI / SCH, B_SZ), 64, 0, stream>>>(xc, zb, Bm, Cm, A_log, Dv, yg);

  // 5) out = yg @ W_out + b_out, pure bf16 MFMA (BN=64)
  gemm_t<64, false, false><<<dim3(DM / 64, M_SZ / 128), 256, 0, stream>>>(
      yg, nullptr, DI, WoT, nullptr, DI, b_out, out, nullptr, DM, DI);
}